// Round 1
// baseline (237.142 us; speedup 1.0000x reference)
//
#include <hip/hip_runtime.h>

// EdgeDecoder: out[e] = relu(BN(W_a x[src] + W_b x[dst] + b1)) . w2 + b2
// Strategy: precompute UV[i] = [W_a x_i | W_b x_i] (bf16, 51.2MB in ws),
// then two cheap edge passes (stats, output) gathering from cache-resident UV.
// Requires ~51.3 MB of d_ws.

#define H 128
#define NN 256
static constexpr int M_NODES = 100000;
static constexpr int E_EDGES = 600000;

typedef __attribute__((ext_vector_type(8))) short bf16x8;
typedef __attribute__((ext_vector_type(4))) float f32x4;

__device__ __forceinline__ unsigned short f2bf(float f) {
    unsigned u = __float_as_uint(f);
    unsigned r = u + 0x7fffu + ((u >> 16) & 1u);   // RNE
    return (unsigned short)(r >> 16);
}
__device__ __forceinline__ float bflo(unsigned u) { return __uint_as_float(u << 16); }
__device__ __forceinline__ float bfhi(unsigned u) { return __uint_as_float(u & 0xffff0000u); }

// ---------------- K0: pack w1 -> Bt[n][k] bf16 (n<128: w1[n][k]; n>=128: w1[n-128][128+k]); zero stats
__global__ __launch_bounds__(256) void k0_prep(const float* __restrict__ w1,
                                               unsigned short* __restrict__ Bt,
                                               float* __restrict__ stats /*256 floats*/) {
    int idx = blockIdx.x * 256 + threadIdx.x;      // 0..32767
    int n = idx >> 7, k = idx & 127;
    float v = (n < 128) ? w1[n * 256 + k] : w1[(n - 128) * 256 + 128 + k];
    Bt[idx] = f2bf(v);                              // Bt[n*128 + k]
    if (idx < 256) stats[idx] = 0.f;
}

// ---------------- K1: UV = X @ Bt^T  (M x 256), bf16 out, MFMA 16x16x32
__global__ __launch_bounds__(256) void k1_uv(const float* __restrict__ x,
                                             const unsigned short* __restrict__ Bt,
                                             unsigned short* __restrict__ UV) {
    __shared__ __align__(16) unsigned short A_lds[64 * 136];  // 64 rows x 128 k, pad +8
    const int m0 = blockIdx.x * 64;
    const int t = threadIdx.x;

    // stage A tile: 64 rows x 128 cols fp32 -> bf16 LDS
    #pragma unroll
    for (int it = 0; it < 8; ++it) {
        int idx = t + it * 256;           // 0..2047 float4-slots
        int r = idx >> 5;                 // row 0..63
        int c4 = idx & 31;                // which float4 in row
        float4 v = make_float4(0.f, 0.f, 0.f, 0.f);
        int row = m0 + r;
        if (row < M_NODES) v = *(const float4*)(x + row * H + c4 * 4);
        unsigned short* p = &A_lds[r * 136 + c4 * 4];
        p[0] = f2bf(v.x); p[1] = f2bf(v.y); p[2] = f2bf(v.z); p[3] = f2bf(v.w);
    }
    __syncthreads();

    const int wave = t >> 6, lane = t & 63;
    const int r16 = lane & 15, q = lane >> 4;
    const int c0 = wave * 64;

    // B fragments: lane holds B[k=8q+j][n=c0+16ct+r16] == Bt[n][k0..k0+8), L2-hot
    bf16x8 bfr[4][4];
    #pragma unroll
    for (int ct = 0; ct < 4; ++ct) {
        int n = c0 + ct * 16 + r16;
        #pragma unroll
        for (int ks = 0; ks < 4; ++ks) {
            int k0 = ks * 32 + q * 8;
            bfr[ct][ks] = *(const bf16x8*)(Bt + n * H + k0);
        }
    }

    f32x4 acc[4][4];
    #pragma unroll
    for (int a = 0; a < 4; ++a)
        #pragma unroll
        for (int b = 0; b < 4; ++b) acc[a][b] = (f32x4){0.f, 0.f, 0.f, 0.f};

    #pragma unroll
    for (int rt = 0; rt < 4; ++rt) {
        bf16x8 afr[4];
        #pragma unroll
        for (int ks = 0; ks < 4; ++ks)
            afr[ks] = *(const bf16x8*)&A_lds[(rt * 16 + r16) * 136 + ks * 32 + q * 8];
        #pragma unroll
        for (int ct = 0; ct < 4; ++ct)
            #pragma unroll
            for (int ks = 0; ks < 4; ++ks)
                acc[rt][ct] = __builtin_amdgcn_mfma_f32_16x16x32_bf16(afr[ks], bfr[ct][ks], acc[rt][ct], 0, 0, 0);
    }

    // store: C/D layout col=lane&15, row=4*quad+reg  [m89-verified]
    #pragma unroll
    for (int rt = 0; rt < 4; ++rt)
        #pragma unroll
        for (int ct = 0; ct < 4; ++ct) {
            int col = c0 + ct * 16 + r16;
            #pragma unroll
            for (int rg = 0; rg < 4; ++rg) {
                int row = m0 + rt * 16 + q * 4 + rg;
                if (row < M_NODES) UV[row * NN + col] = f2bf(acc[rt][ct][rg]);
            }
        }
}

// ---------------- K2: per-edge z = u[src]+v[dst]+b1; accumulate sum, sumsq per feature
__global__ __launch_bounds__(256) void k2_stats(const unsigned short* __restrict__ UV,
                                                const int* __restrict__ ei,
                                                const float* __restrict__ b1,
                                                float* __restrict__ gsum,
                                                float* __restrict__ gss) {
    __shared__ float ssum[128], sss[128];
    const int t = threadIdx.x;
    if (t < 128) { ssum[t] = 0.f; sss[t] = 0.f; }
    __syncthreads();

    const int sub = t & 15;                         // 16 lanes per edge
    const int gid = (blockIdx.x * 256 + t) >> 4;
    const int ngroups = gridDim.x * 16;

    float b1r[8];
    #pragma unroll
    for (int j = 0; j < 8; ++j) b1r[j] = b1[sub * 8 + j];

    float asum[8] = {0, 0, 0, 0, 0, 0, 0, 0};
    float ass[8]  = {0, 0, 0, 0, 0, 0, 0, 0};

    for (int e = gid; e < E_EDGES; e += ngroups) {
        int s = ei[2 * e], d = ei[2 * e + 1];
        uint4 uu = *(const uint4*)(UV + s * NN + sub * 8);
        uint4 vv = *(const uint4*)(UV + d * NN + 128 + sub * 8);
        #define ACC2(ua, va, j0)                                              \
        {   float z0 = bflo(ua) + bflo(va) + b1r[j0];                         \
            asum[j0] += z0; ass[j0] += z0 * z0;                               \
            float z1 = bfhi(ua) + bfhi(va) + b1r[j0 + 1];                     \
            asum[j0 + 1] += z1; ass[j0 + 1] += z1 * z1; }
        ACC2(uu.x, vv.x, 0) ACC2(uu.y, vv.y, 2) ACC2(uu.z, vv.z, 4) ACC2(uu.w, vv.w, 6)
        #undef ACC2
    }
    #pragma unroll
    for (int j = 0; j < 8; ++j) {
        atomicAdd(&ssum[sub * 8 + j], asum[j]);
        atomicAdd(&sss[sub * 8 + j], ass[j]);
    }
    __syncthreads();
    if (t < 128) atomicAdd(&gsum[t], ssum[t]);
    else         atomicAdd(&gss[t - 128], sss[t - 128]);
}

// ---------------- K3: finalize BN affine: A = gamma*rsqrt(var+eps), C = beta - mean*A
__global__ void k3_fin(const float* __restrict__ gsum, const float* __restrict__ gss,
                       const float* __restrict__ gamma, const float* __restrict__ beta,
                       float* __restrict__ Ab, float* __restrict__ Cb) {
    int t = threadIdx.x;  // 128
    float mean = gsum[t] * (1.f / E_EDGES);
    float var  = gss[t] * (1.f / E_EDGES) - mean * mean;
    float inv  = rsqrtf(var + 1e-5f);
    float a = gamma[t] * inv;
    Ab[t] = a;
    Cb[t] = beta[t] - mean * a;
}

// ---------------- K4: out[e] = sum_h relu(z*A + C) * w2 + b2
__global__ __launch_bounds__(256) void k4_out(const unsigned short* __restrict__ UV,
                                              const int* __restrict__ ei,
                                              const float* __restrict__ b1,
                                              const float* __restrict__ Ab,
                                              const float* __restrict__ Cb,
                                              const float* __restrict__ w2,
                                              const float* __restrict__ b2,
                                              float* __restrict__ out) {
    const int t = threadIdx.x;
    const int sub = t & 15;
    const int gid = (blockIdx.x * 256 + t) >> 4;
    const int ngroups = gridDim.x * 16;

    float b1r[8], Ar[8], Cr[8], wr[8];
    #pragma unroll
    for (int j = 0; j < 8; ++j) {
        int h = sub * 8 + j;
        b1r[j] = b1[h]; Ar[j] = Ab[h]; Cr[j] = Cb[h]; wr[j] = w2[h];
    }
    const float bb2 = b2[0];

    for (int e = gid; e < E_EDGES; e += ngroups) {
        int s = ei[2 * e], d = ei[2 * e + 1];
        uint4 uu = *(const uint4*)(UV + s * NN + sub * 8);
        uint4 vv = *(const uint4*)(UV + d * NN + 128 + sub * 8);
        float p = 0.f;
        #define DOT2(ua, va, j0)                                              \
        {   float z0 = bflo(ua) + bflo(va) + b1r[j0];                         \
            p += fmaxf(fmaf(z0, Ar[j0], Cr[j0]), 0.f) * wr[j0];               \
            float z1 = bfhi(ua) + bfhi(va) + b1r[j0 + 1];                     \
            p += fmaxf(fmaf(z1, Ar[j0 + 1], Cr[j0 + 1]), 0.f) * wr[j0 + 1]; }
        DOT2(uu.x, vv.x, 0) DOT2(uu.y, vv.y, 2) DOT2(uu.z, vv.z, 4) DOT2(uu.w, vv.w, 6)
        #undef DOT2
        p += __shfl_xor(p, 1);
        p += __shfl_xor(p, 2);
        p += __shfl_xor(p, 4);
        p += __shfl_xor(p, 8);
        if (sub == 0) out[e] = p + bb2;
    }
}

extern "C" void kernel_launch(void* const* d_in, const int* in_sizes, int n_in,
                              void* d_out, int out_size, void* d_ws, size_t ws_size,
                              hipStream_t stream) {
    const float* x     = (const float*)d_in[0];
    const int*   ei    = (const int*)d_in[1];     // edge_index as int32 per harness convention
    const float* w1    = (const float*)d_in[2];
    const float* b1    = (const float*)d_in[3];
    const float* gamma = (const float*)d_in[4];
    const float* beta  = (const float*)d_in[5];
    const float* w2    = (const float*)d_in[6];
    const float* b2    = (const float*)d_in[7];
    float* out = (float*)d_out;

    char* w = (char*)d_ws;
    unsigned short* UV = (unsigned short*)w;                       // 51,200,000 B
    unsigned short* Bt = (unsigned short*)(w + 51200000);          // 65,536 B
    float* gsum = (float*)(w + 51265536);                          // 128 f
    float* gss  = gsum + 128;                                      // 128 f
    float* Ab   = (float*)(w + 51266560);                          // 128 f
    float* Cb   = Ab + 128;                                        // 128 f

    k0_prep<<<128, 256, 0, stream>>>(w1, Bt, gsum);
    k1_uv<<<(M_NODES + 63) / 64, 256, 0, stream>>>(x, Bt, UV);
    k2_stats<<<1024, 256, 0, stream>>>(UV, ei, b1, gsum, gss);
    k3_fin<<<1, 128, 0, stream>>>(gsum, gss, gamma, beta, Ab, Cb);
    k4_out<<<1024, 256, 0, stream>>>(UV, ei, b1, Ab, Cb, w2, b2, out);
}